// Round 14
// baseline (394.294 us; speedup 1.0000x reference)
//
#include <hip/hip_runtime.h>
#include <stdint.h>

#define SEQ 2048
#define BSZ 4
#define EMB 1024
#define NH  16
#define HD  64
#define BH  (BSZ*NH)        // 64
#define MROWS (SEQ*BSZ)     // 8192

// exp(x*0.125) == exp2(x * 0.125*log2(e))
#define EXPSCL 0.18033688011112042f

typedef __attribute__((ext_vector_type(8))) short short8;
typedef __attribute__((ext_vector_type(4))) float f32x4;
typedef __attribute__((ext_vector_type(4))) unsigned short us4;

__device__ __forceinline__ unsigned short f2bf(float f) {
  unsigned u = __float_as_uint(f);
  u += 0x7fffu + ((u >> 16) & 1u);          // round-to-nearest-even
  return (unsigned short)(u >> 16);
}

#define GLDS(g, l) __builtin_amdgcn_global_load_lds( \
    (const __attribute__((address_space(1))) void*)(g), \
    (__attribute__((address_space(3))) void*)(l), 16, 0, 0)

// ---------------- fused f32 -> bf16 convert (x, W_in, W_out in one launch) ----------------
__global__ void k_cvt3(const float* __restrict__ x, const float* __restrict__ wi,
                       const float* __restrict__ wo, unsigned short* __restrict__ xb,
                       unsigned short* __restrict__ wib, unsigned short* __restrict__ wob) {
  const int n0 = MROWS*EMB/4, n1 = 3*EMB*EMB/4, n2 = EMB*EMB/4;
  int i = blockIdx.x * blockDim.x + threadIdx.x;
  const int stride = gridDim.x * blockDim.x;
  for (; i < n0+n1+n2; i += stride) {
    const float* src; unsigned short* dst; int j;
    if (i < n0)           { src = x;  dst = xb;  j = i; }
    else if (i < n0+n1)   { src = wi; dst = wib; j = i - n0; }
    else                  { src = wo; dst = wob; j = i - n0 - n1; }
    float4 v = reinterpret_cast<const float4*>(src)[j];
    us4 o;
    o[0] = f2bf(v.x); o[1] = f2bf(v.y); o[2] = f2bf(v.z); o[3] = f2bf(v.w);
    reinterpret_cast<us4*>(dst)[j] = o;
  }
}

// ---------------- 128x128-tile bt GEMM: C = A * B^T (+bias) ----------------
// MODE 0: f32 out. MODE 1: QKV scatter; V written TRANSPOSED ([bh][d][s]).
template<int MODE>
__global__ __launch_bounds__(256, 2) void k_gemm_bt(
    const unsigned short* __restrict__ A, const unsigned short* __restrict__ B,
    const float* __restrict__ bias, float* __restrict__ outF,
    unsigned short* __restrict__ qb, unsigned short* __restrict__ kb,
    unsigned short* __restrict__ vb, int M, int N, int K)
{
  __shared__ unsigned short As[128*32];
  __shared__ unsigned short Bs[128*32];
  const int tid  = threadIdx.x;
  const int lane = tid & 63;
  const int wid  = tid >> 6;
  const int wr = wid >> 1, wc = wid & 1;
  const int r0 = blockIdx.y * 128;
  const int c0 = blockIdx.x * 128;
  const int lr = lane & 15;
  const int hi = lane >> 4;

  f32x4 acc[4][4];
  #pragma unroll
  for (int i = 0; i < 4; i++)
    #pragma unroll
    for (int j = 0; j < 4; j++) acc[i][j] = f32x4{0.f,0.f,0.f,0.f};

  const int nk = K >> 5;
  for (int kt = 0; kt < nk; ++kt) {
    #pragma unroll
    for (int j = 0; j < 2; ++j) {
      int e = (wid*2 + j)*512 + lane*8;
      int row = e >> 5, kk = e & 31;
      GLDS(A + (size_t)(r0 + row)*K + kt*32 + kk, &As[(wid*2+j)*512]);
      GLDS(B + (size_t)(c0 + row)*K + kt*32 + kk, &Bs[(wid*2+j)*512]);
    }
    __syncthreads();
    short8 af[4], bf[4];
    #pragma unroll
    for (int i = 0; i < 4; i++) af[i] = *(const short8*)&As[(wr*64 + i*16 + lr)*32 + hi*8];
    #pragma unroll
    for (int j = 0; j < 4; j++) bf[j] = *(const short8*)&Bs[(wc*64 + j*16 + lr)*32 + hi*8];
    #pragma unroll
    for (int i = 0; i < 4; i++)
      #pragma unroll
      for (int j = 0; j < 4; j++)
        acc[i][j] = __builtin_amdgcn_mfma_f32_16x16x32_bf16(af[i], bf[j], acc[i][j], 0, 0, 0);
    __syncthreads();
  }

  #pragma unroll
  for (int i = 0; i < 4; i++) {
    #pragma unroll
    for (int j = 0; j < 4; j++) {
      #pragma unroll
      for (int r = 0; r < 4; r++) {
        int row = r0 + wr*64 + i*16 + hi*4 + r;
        int col = c0 + wc*64 + j*16 + lr;
        float v = acc[i][j][r] + bias[col];
        if (MODE == 0) {
          outF[(size_t)row*N + col] = v;
        } else {
          int s = row >> 2, b = row & 3;
          int which = col >> 10, h = (col >> 6) & 15, d = col & 63;
          unsigned short bvv = f2bf(v);
          if (which == 0)      qb[((size_t)(b*NH + h)*SEQ + s)*HD + d] = bvv;
          else if (which == 1) kb[((size_t)(b*NH + h)*SEQ + s)*HD + d] = bvv;
          else                 vb[((size_t)(b*NH + h)*HD + d)*SEQ + s] = bvv;  // Vt direct
        }
      }
    }
  }
}

// ---------------- fused attention v5 + exp2-fold: counted vmcnt ----------------
// Counting discipline: s_waitcnt vmcnt(N) guarantees all but the newest N VMEM
// ops retired -> to require op X complete, N = #ops issued AFTER X.
__global__ __launch_bounds__(512, 4) void k_attn5(
    const unsigned short* __restrict__ Q, const unsigned short* __restrict__ Kb,
    const unsigned short* __restrict__ Vt, float* __restrict__ P,
    unsigned short* __restrict__ ctx)
{
  __shared__ unsigned short Ks[3][4096];   // [64 k][64 d] swizzled, 8KB each
  __shared__ unsigned short Vs[3][4096];   // [64 d][64 k] swizzled, 8KB each
  __shared__ float Pf[8][1024];            // per-wave [16 q][64 k] f32, swizzled

  const int i   = blockIdx.x;
  const int bh  = i & 63;                  // XCD = bh & 7 for all 16 row-blocks
  const int rb  = i >> 6;

  const int tid = threadIdx.x;
  const int lane = tid & 63, w = tid >> 6;
  const int lr = lane & 15, hi = lane >> 4;
  const int q0 = rb * 128 + w * 16;
  const size_t qkBase = (size_t)bh * SEQ * HD;
  const size_t vtBase = (size_t)bh * HD * SEQ;

  // staging: thread t fills LDS bytes [t*16, t*16+16); global col pre-swizzled
  const int srow = tid >> 3;                                      // 0..63
  const int scol = ((((tid & 7) * 16) ^ ((srow & 7) << 4)) >> 1); // elems
  const int swz  = (lr & 7) << 4;

  #define STG_K(buf, kt) GLDS(Kb + qkBase + (size_t)((kt)*64 + srow)*HD + scol, \
                              (unsigned short*)Ks[buf] + tid*8)
  #define STG_V(buf, kt) GLDS(Vt + vtBase + (size_t)srow*SEQ + (kt)*64 + scol, \
                              (unsigned short*)Vs[buf] + tid*8)
  #define WAITV(n) asm volatile("s_waitcnt vmcnt(" #n ")" ::: "memory")
  #define BARRIER __builtin_amdgcn_s_barrier(); asm volatile("" ::: "memory")

  // Q B-fragments (two K=32 d-slices)
  short8 bq0 = *(const short8*)&Q[qkBase + (size_t)(q0 + lr)*HD + hi*8];
  short8 bq1 = *(const short8*)&Q[qkBase + (size_t)(q0 + lr)*HD + 32 + hi*8];

  // ---- pass 1: row sums of exp2(s*c) ----
  STG_K(0, 0); STG_K(1, 1);
  WAITV(1);                        // K0 landed (K1 may float)
  BARRIER;
  float lsum = 0.f;
  {
    int cur = 0;
    for (int kt = 0; kt < 32; ++kt) {
      const char* kbase = (const char*)Ks[cur];
      #pragma unroll
      for (int ct = 0; ct < 4; ++ct) {
        const int rowb = (ct*16 + lr) * 128;
        short8 ak0 = *(const short8*)(kbase + ((rowb + hi*16) ^ swz));
        short8 ak1 = *(const short8*)(kbase + ((rowb + 64 + hi*16) ^ swz));
        f32x4 z = f32x4{0.f,0.f,0.f,0.f};
        z = __builtin_amdgcn_mfma_f32_16x16x32_bf16(ak0, bq0, z, 0, 0, 0);
        z = __builtin_amdgcn_mfma_f32_16x16x32_bf16(ak1, bq1, z, 0, 0, 0);
        lsum += exp2f(z[0]*EXPSCL) + exp2f(z[1]*EXPSCL)
              + exp2f(z[2]*EXPSCL) + exp2f(z[3]*EXPSCL);
      }
      int bs = cur + 2; if (bs >= 3) bs -= 3;
      if (kt < 30) {
        STG_K(bs, kt + 2);
        WAITV(1);                  // K(kt+1) landed; K(kt+2) floats
      } else {
        WAITV(0);
      }
      BARRIER;
      cur = (cur >= 2) ? 0 : cur + 1;
    }
  }
  float lv = lsum;
  lv += __shfl_xor(lv, 16);
  lv += __shfl_xor(lv, 32);
  const float li = 1.0f / lv;        // 1/l for row q0+lr

  // ---- pass 2: recompute, staged coalesced P store, PV accumulate ----
  f32x4 o[4];
  #pragma unroll
  for (int d = 0; d < 4; ++d) o[d] = f32x4{0.f,0.f,0.f,0.f};

  float* pout = P + ((size_t)bh*SEQ + q0)*SEQ;
  char* pfw = (char*)Pf[w];

  STG_K(0, 0); STG_V(0, 0); STG_K(1, 1); STG_V(1, 1);
  WAITV(2);                        // K0,V0 landed (K1,V1 float)
  BARRIER;
  {
    int cur = 0;
    for (int kt = 0; kt < 32; ++kt) {
      const char* kbase = (const char*)Ks[cur];
      const char* vbase = (const char*)Vs[cur];
      // QK + exp -> Pf (swizzled f32 tile)
      #pragma unroll
      for (int ct = 0; ct < 4; ++ct) {
        const int rowb = (ct*16 + lr) * 128;
        short8 ak0 = *(const short8*)(kbase + ((rowb + hi*16) ^ swz));
        short8 ak1 = *(const short8*)(kbase + ((rowb + 64 + hi*16) ^ swz));
        f32x4 z = f32x4{0.f,0.f,0.f,0.f};
        z = __builtin_amdgcn_mfma_f32_16x16x32_bf16(ak0, bq0, z, 0, 0, 0);
        z = __builtin_amdgcn_mfma_f32_16x16x32_bf16(ak1, bq1, z, 0, 0, 0);
        f32x4 e;
        #pragma unroll
        for (int r = 0; r < 4; r++) e[r] = exp2f(z[r]*EXPSCL) * li;
        *(f32x4*)(pfw + ((((ct*4 + hi) ^ lr) << 4) + lr*256)) = e;
      }
      // coalesced NT P stores: 4 insts, each 4 rows x 256B
      #pragma unroll
      for (int j = 0; j < 4; ++j) {
        const int row = j*4 + hi;
        f32x4 pv4 = *(const f32x4*)(pfw + (row*256 + ((lr ^ row) << 4)));
        __builtin_nontemporal_store(pv4,
            (f32x4*)&pout[(size_t)row*SEQ + kt*64 + lr*4]);
      }
      // PV: pa frags from Pf (cvt f32->bf16), V frags from Vs
      #pragma unroll
      for (int s = 0; s < 2; ++s) {
        const int c0 = s*8 + hi*2;
        f32x4 f0 = *(const f32x4*)(pfw + (lr*256 + (((c0    ) ^ lr) << 4)));
        f32x4 f1 = *(const f32x4*)(pfw + (lr*256 + (((c0 + 1) ^ lr) << 4)));
        short8 pa;
        #pragma unroll
        for (int r = 0; r < 4; r++) { pa[r] = (short)f2bf(f0[r]); pa[4+r] = (short)f2bf(f1[r]); }
        #pragma unroll
        for (int dt = 0; dt < 4; ++dt) {
          const int rowb = (dt*16 + lr) * 128;
          short8 vb = *(const short8*)(vbase + ((rowb + s*64 + hi*16) ^ swz));
          o[dt] = __builtin_amdgcn_mfma_f32_16x16x32_bf16(pa, vb, o[dt], 0, 0, 0);
        }
      }
      if (kt < 30) {
        int bs = cur + 2; if (bs >= 3) bs -= 3;
        STG_K(bs, kt + 2); STG_V(bs, kt + 2);
        WAITV(6);                  // K/V(kt+1) landed (newer: 4 stores + 2 GLDS)
        BARRIER;
      } else if (kt == 30) {
        WAITV(4);                  // K/V(31) landed (newer: 4 stores)
        BARRIER;
      }
      // kt == 31: nothing reads K/V LDS afterwards -> no wait, no barrier
      cur = (cur >= 2) ? 0 : cur + 1;
    }
  }

  // ---- ctx store: [s*B + b][h*64 + d] bf16 ----
  const int b = bh >> 4, h = bh & 15;
  #pragma unroll
  for (int dt = 0; dt < 4; ++dt)
    #pragma unroll
    for (int r = 0; r < 4; r++) {
      int s = q0 + hi*4 + r;
      ctx[((size_t)s*BSZ + b)*EMB + h*HD + dt*16 + lr] = f2bf(o[dt][r]);
    }
  #undef STG_K
  #undef STG_V
  #undef WAITV
  #undef BARRIER
}

extern "C" void kernel_launch(void* const* d_in, const int* in_sizes, int n_in,
                              void* d_out, int out_size, void* d_ws, size_t ws_size,
                              hipStream_t stream) {
  const float* x     = (const float*)d_in[0];
  const float* W_in  = (const float*)d_in[1];
  const float* b_in  = (const float*)d_in[2];
  const float* W_out = (const float*)d_in[3];
  const float* b_out = (const float*)d_in[4];
  float* out   = (float*)d_out;
  float* attnP = out + (size_t)MROWS*EMB;

  char* ws = (char*)d_ws;
  size_t off = 0;
  auto alloc = [&](size_t bytes) { char* p = ws + off; off += (bytes + 255) & ~255ULL; return p; };
  unsigned short* Xbf    = (unsigned short*)alloc((size_t)MROWS*EMB*2);
  unsigned short* Winbf  = (unsigned short*)alloc((size_t)3*EMB*EMB*2);
  unsigned short* Woutbf = (unsigned short*)alloc((size_t)EMB*EMB*2);
  unsigned short* Qb  = (unsigned short*)alloc((size_t)BH*SEQ*HD*2);
  unsigned short* Kbf = (unsigned short*)alloc((size_t)BH*SEQ*HD*2);
  unsigned short* Vt  = (unsigned short*)alloc((size_t)BH*SEQ*HD*2);
  unsigned short* ctx = Xbf;   // Xbf dead after QKV GEMM -> reuse

  k_cvt3<<<2048, 256, 0, stream>>>(x, W_in, W_out, Xbf, Winbf, Woutbf);

  k_gemm_bt<1><<<dim3(3*EMB/128, MROWS/128), 256, 0, stream>>>(
      Xbf, Winbf, b_in, nullptr, Qb, Kbf, Vt, MROWS, 3*EMB, EMB);

  k_attn5<<<1024, 512, 0, stream>>>(Qb, Kbf, Vt, attnP, ctx);

  k_gemm_bt<0><<<dim3(EMB/128, MROWS/128), 256, 0, stream>>>(
      ctx, Woutbf, b_out, out, nullptr, nullptr, nullptr, MROWS, EMB, EMB);
}

// Round 15
// 370.927 us; speedup vs baseline: 1.0630x; 1.0630x over previous
//
#include <hip/hip_runtime.h>
#include <stdint.h>

#define SEQ 2048
#define BSZ 4
#define EMB 1024
#define NH  16
#define HD  64
#define BH  (BSZ*NH)        // 64
#define MROWS (SEQ*BSZ)     // 8192

typedef __attribute__((ext_vector_type(8))) short short8;
typedef __attribute__((ext_vector_type(4))) float f32x4;
typedef __attribute__((ext_vector_type(4))) unsigned short us4;

__device__ __forceinline__ unsigned short f2bf(float f) {
  unsigned u = __float_as_uint(f);
  u += 0x7fffu + ((u >> 16) & 1u);          // round-to-nearest-even
  return (unsigned short)(u >> 16);
}

#define GLDS(g, l) __builtin_amdgcn_global_load_lds( \
    (const __attribute__((address_space(1))) void*)(g), \
    (__attribute__((address_space(3))) void*)(l), 16, 0, 0)

// ---------------- f32 -> bf16 convert (vectorized) ----------------
__global__ void k_cvt(const float* __restrict__ in, unsigned short* __restrict__ out, int n4) {
  int i = blockIdx.x * blockDim.x + threadIdx.x;
  int stride = gridDim.x * blockDim.x;
  for (; i < n4; i += stride) {
    float4 v = reinterpret_cast<const float4*>(in)[i];
    us4 o;
    o[0] = f2bf(v.x); o[1] = f2bf(v.y); o[2] = f2bf(v.z); o[3] = f2bf(v.w);
    reinterpret_cast<us4*>(out)[i] = o;
  }
}

// ---------------- 128x128-tile bt GEMM: C = A * B^T (+bias) ----------------
template<int MODE>
__global__ __launch_bounds__(256, 2) void k_gemm_bt(
    const unsigned short* __restrict__ A, const unsigned short* __restrict__ B,
    const float* __restrict__ bias, float* __restrict__ outF,
    unsigned short* __restrict__ qb, unsigned short* __restrict__ kb,
    unsigned short* __restrict__ vb, int M, int N, int K)
{
  __shared__ unsigned short As[128*32];
  __shared__ unsigned short Bs[128*32];
  const int tid  = threadIdx.x;
  const int lane = tid & 63;
  const int wid  = tid >> 6;
  const int wr = wid >> 1, wc = wid & 1;
  const int r0 = blockIdx.y * 128;
  const int c0 = blockIdx.x * 128;
  const int lr = lane & 15;
  const int hi = lane >> 4;

  f32x4 acc[4][4];
  #pragma unroll
  for (int i = 0; i < 4; i++)
    #pragma unroll
    for (int j = 0; j < 4; j++) acc[i][j] = f32x4{0.f,0.f,0.f,0.f};

  const int nk = K >> 5;
  for (int kt = 0; kt < nk; ++kt) {
    #pragma unroll
    for (int j = 0; j < 2; ++j) {
      int e = (wid*2 + j)*512 + lane*8;
      int row = e >> 5, kk = e & 31;
      GLDS(A + (size_t)(r0 + row)*K + kt*32 + kk, &As[(wid*2+j)*512]);
      GLDS(B + (size_t)(c0 + row)*K + kt*32 + kk, &Bs[(wid*2+j)*512]);
    }
    __syncthreads();
    short8 af[4], bf[4];
    #pragma unroll
    for (int i = 0; i < 4; i++) af[i] = *(const short8*)&As[(wr*64 + i*16 + lr)*32 + hi*8];
    #pragma unroll
    for (int j = 0; j < 4; j++) bf[j] = *(const short8*)&Bs[(wc*64 + j*16 + lr)*32 + hi*8];
    #pragma unroll
    for (int i = 0; i < 4; i++)
      #pragma unroll
      for (int j = 0; j < 4; j++)
        acc[i][j] = __builtin_amdgcn_mfma_f32_16x16x32_bf16(af[i], bf[j], acc[i][j], 0, 0, 0);
    __syncthreads();
  }

  #pragma unroll
  for (int i = 0; i < 4; i++) {
    #pragma unroll
    for (int j = 0; j < 4; j++) {
      #pragma unroll
      for (int r = 0; r < 4; r++) {
        int row = r0 + wr*64 + i*16 + hi*4 + r;
        int col = c0 + wc*64 + j*16 + lr;
        float v = acc[i][j][r] + bias[col];
        if (MODE == 0) {
          outF[(size_t)row*N + col] = v;
        } else {
          int s = row >> 2, b = row & 3;
          int which = col >> 10, h = (col >> 6) & 15, d = col & 63;
          unsigned short bvv = f2bf(v);
          unsigned short* dst = (which == 0) ? qb : (which == 1) ? kb : vb;
          dst[((size_t)(b*NH + h)*SEQ + s)*HD + d] = bvv;
        }
      }
    }
  }
}

// ---------------- V [bh][s][d] -> Vt [bh][d][s] ----------------
__global__ void k_transposeV(const unsigned short* __restrict__ V, unsigned short* __restrict__ Vt) {
  __shared__ unsigned short T[64][65];
  const int bh = blockIdx.y;
  const int s0 = blockIdx.x * 64;
  const int t = threadIdx.x;             // 0..255, 16 elems each
  const int e = t * 16;
  {
    const int s = e >> 6, d0 = e & 63;
    short8 v0 = *(const short8*)&V[((size_t)bh*SEQ + s0 + s)*HD + d0];
    short8 v1 = *(const short8*)&V[((size_t)bh*SEQ + s0 + s)*HD + d0 + 8];
    #pragma unroll
    for (int q = 0; q < 8; q++) { T[s][d0+q] = (unsigned short)v0[q]; T[s][d0+8+q] = (unsigned short)v1[q]; }
  }
  __syncthreads();
  {
    const int d = e >> 6, sl = e & 63;
    short8 w0, w1;
    #pragma unroll
    for (int q = 0; q < 8; q++) { w0[q] = (short)T[sl+q][d]; w1[q] = (short)T[sl+8+q][d]; }
    *(short8*)&Vt[((size_t)bh*HD + d)*SEQ + s0 + sl]     = w0;
    *(short8*)&Vt[((size_t)bh*HD + d)*SEQ + s0 + sl + 8] = w1;
  }
}

// ---------------- fused attention v5: v4 with CORRECT counted vmcnt ----------------
// Counting discipline: s_waitcnt vmcnt(N) guarantees all but the newest N VMEM
// ops retired -> to require op X complete, N = #ops issued AFTER X.
// Pass 1 (1 GLDS/iter): after issuing G(kt+2), G(kt+1) has 1 newer op -> vmcnt(1).
// Pass 2 (4 NT stores + 2 GLDS/iter): G(kt+1) has 4+2=6 newer -> vmcnt(6);
// prologue K0,V0 have 2 newer (K1,V1) -> vmcnt(2); kt=30 tail -> vmcnt(4).
__global__ __launch_bounds__(512, 4) void k_attn5(
    const unsigned short* __restrict__ Q, const unsigned short* __restrict__ Kb,
    const unsigned short* __restrict__ Vt, float* __restrict__ P,
    unsigned short* __restrict__ ctx)
{
  __shared__ unsigned short Ks[3][4096];   // [64 k][64 d] swizzled, 8KB each
  __shared__ unsigned short Vs[3][4096];   // [64 d][64 k] swizzled, 8KB each
  __shared__ float Pf[8][1024];            // per-wave [16 q][64 k] f32, swizzled

  const int i   = blockIdx.x;
  const int bh  = i & 63;                  // XCD = bh & 7 for all 16 row-blocks
  const int rb  = i >> 6;

  const int tid = threadIdx.x;
  const int lane = tid & 63, w = tid >> 6;
  const int lr = lane & 15, hi = lane >> 4;
  const int q0 = rb * 128 + w * 16;
  const size_t qkBase = (size_t)bh * SEQ * HD;
  const size_t vtBase = (size_t)bh * HD * SEQ;

  // staging: thread t fills LDS bytes [t*16, t*16+16); global col pre-swizzled
  const int srow = tid >> 3;                                      // 0..63
  const int scol = ((((tid & 7) * 16) ^ ((srow & 7) << 4)) >> 1); // elems
  const int swz  = (lr & 7) << 4;

  #define STG_K(buf, kt) GLDS(Kb + qkBase + (size_t)((kt)*64 + srow)*HD + scol, \
                              (unsigned short*)Ks[buf] + tid*8)
  #define STG_V(buf, kt) GLDS(Vt + vtBase + (size_t)srow*SEQ + (kt)*64 + scol, \
                              (unsigned short*)Vs[buf] + tid*8)
  #define WAITV(n) asm volatile("s_waitcnt vmcnt(" #n ")" ::: "memory")
  #define BARRIER __builtin_amdgcn_s_barrier(); asm volatile("" ::: "memory")

  // Q B-fragments (two K=32 d-slices)
  short8 bq0 = *(const short8*)&Q[qkBase + (size_t)(q0 + lr)*HD + hi*8];
  short8 bq1 = *(const short8*)&Q[qkBase + (size_t)(q0 + lr)*HD + 32 + hi*8];

  // ---- pass 1: row sums of exp(s/8) ----
  STG_K(0, 0); STG_K(1, 1);
  WAITV(1);                        // K0 landed (K1 may float)
  BARRIER;
  float lsum = 0.f;
  {
    int cur = 0;
    for (int kt = 0; kt < 32; ++kt) {
      const char* kbase = (const char*)Ks[cur];
      #pragma unroll
      for (int ct = 0; ct < 4; ++ct) {
        const int rowb = (ct*16 + lr) * 128;
        short8 ak0 = *(const short8*)(kbase + ((rowb + hi*16) ^ swz));
        short8 ak1 = *(const short8*)(kbase + ((rowb + 64 + hi*16) ^ swz));
        f32x4 z = f32x4{0.f,0.f,0.f,0.f};
        z = __builtin_amdgcn_mfma_f32_16x16x32_bf16(ak0, bq0, z, 0, 0, 0);
        z = __builtin_amdgcn_mfma_f32_16x16x32_bf16(ak1, bq1, z, 0, 0, 0);
        lsum += __expf(z[0]*0.125f) + __expf(z[1]*0.125f)
              + __expf(z[2]*0.125f) + __expf(z[3]*0.125f);
      }
      int bs = cur + 2; if (bs >= 3) bs -= 3;
      if (kt < 30) {
        STG_K(bs, kt + 2);
        WAITV(1);                  // K(kt+1) landed; K(kt+2) floats
      } else {
        WAITV(0);
      }
      BARRIER;
      cur = (cur >= 2) ? 0 : cur + 1;
    }
  }
  float lv = lsum;
  lv += __shfl_xor(lv, 16);
  lv += __shfl_xor(lv, 32);
  const float li = 1.0f / lv;        // 1/l for row q0+lr

  // ---- pass 2: recompute, staged coalesced P store, PV accumulate ----
  f32x4 o[4];
  #pragma unroll
  for (int d = 0; d < 4; ++d) o[d] = f32x4{0.f,0.f,0.f,0.f};

  float* pout = P + ((size_t)bh*SEQ + q0)*SEQ;
  char* pfw = (char*)Pf[w];

  STG_K(0, 0); STG_V(0, 0); STG_K(1, 1); STG_V(1, 1);
  WAITV(2);                        // K0,V0 landed (K1,V1 float)
  BARRIER;
  {
    int cur = 0;
    for (int kt = 0; kt < 32; ++kt) {
      const char* kbase = (const char*)Ks[cur];
      const char* vbase = (const char*)Vs[cur];
      // QK + exp -> Pf (swizzled f32 tile)
      #pragma unroll
      for (int ct = 0; ct < 4; ++ct) {
        const int rowb = (ct*16 + lr) * 128;
        short8 ak0 = *(const short8*)(kbase + ((rowb + hi*16) ^ swz));
        short8 ak1 = *(const short8*)(kbase + ((rowb + 64 + hi*16) ^ swz));
        f32x4 z = f32x4{0.f,0.f,0.f,0.f};
        z = __builtin_amdgcn_mfma_f32_16x16x32_bf16(ak0, bq0, z, 0, 0, 0);
        z = __builtin_amdgcn_mfma_f32_16x16x32_bf16(ak1, bq1, z, 0, 0, 0);
        f32x4 e;
        #pragma unroll
        for (int r = 0; r < 4; r++) e[r] = __expf(z[r]*0.125f) * li;
        *(f32x4*)(pfw + ((((ct*4 + hi) ^ lr) << 4) + lr*256)) = e;
      }
      // coalesced NT P stores: 4 insts, each 4 rows x 256B
      #pragma unroll
      for (int j = 0; j < 4; ++j) {
        const int row = j*4 + hi;
        f32x4 pv4 = *(const f32x4*)(pfw + (row*256 + ((lr ^ row) << 4)));
        __builtin_nontemporal_store(pv4,
            (f32x4*)&pout[(size_t)row*SEQ + kt*64 + lr*4]);
      }
      // PV: pa frags from Pf (cvt f32->bf16), V frags from Vs
      #pragma unroll
      for (int s = 0; s < 2; ++s) {
        const int c0 = s*8 + hi*2;
        f32x4 f0 = *(const f32x4*)(pfw + (lr*256 + (((c0    ) ^ lr) << 4)));
        f32x4 f1 = *(const f32x4*)(pfw + (lr*256 + (((c0 + 1) ^ lr) << 4)));
        short8 pa;
        #pragma unroll
        for (int r = 0; r < 4; r++) { pa[r] = (short)f2bf(f0[r]); pa[4+r] = (short)f2bf(f1[r]); }
        #pragma unroll
        for (int dt = 0; dt < 4; ++dt) {
          const int rowb = (dt*16 + lr) * 128;
          short8 vb = *(const short8*)(vbase + ((rowb + s*64 + hi*16) ^ swz));
          o[dt] = __builtin_amdgcn_mfma_f32_16x16x32_bf16(pa, vb, o[dt], 0, 0, 0);
        }
      }
      if (kt < 30) {
        int bs = cur + 2; if (bs >= 3) bs -= 3;
        STG_K(bs, kt + 2); STG_V(bs, kt + 2);
        WAITV(6);                  // K/V(kt+1) landed (newer: 4 stores + 2 GLDS)
        BARRIER;
      } else if (kt == 30) {
        WAITV(4);                  // K/V(31) landed (newer: 4 stores)
        BARRIER;
      }
      // kt == 31: nothing reads K/V LDS afterwards -> no wait, no barrier
      cur = (cur >= 2) ? 0 : cur + 1;
    }
  }

  // ---- ctx store: [s*B + b][h*64 + d] bf16 ----
  const int b = bh >> 4, h = bh & 15;
  #pragma unroll
  for (int dt = 0; dt < 4; ++dt)
    #pragma unroll
    for (int r = 0; r < 4; r++) {
      int s = q0 + hi*4 + r;
      ctx[((size_t)s*BSZ + b)*EMB + h*HD + dt*16 + lr] = f2bf(o[dt][r]);
    }
  #undef STG_K
  #undef STG_V
  #undef WAITV
  #undef BARRIER
}

extern "C" void kernel_launch(void* const* d_in, const int* in_sizes, int n_in,
                              void* d_out, int out_size, void* d_ws, size_t ws_size,
                              hipStream_t stream) {
  const float* x     = (const float*)d_in[0];
  const float* W_in  = (const float*)d_in[1];
  const float* b_in  = (const float*)d_in[2];
  const float* W_out = (const float*)d_in[3];
  const float* b_out = (const float*)d_in[4];
  float* out   = (float*)d_out;
  float* attnP = out + (size_t)MROWS*EMB;

  char* ws = (char*)d_ws;
  size_t off = 0;
  auto alloc = [&](size_t bytes) { char* p = ws + off; off += (bytes + 255) & ~255ULL; return p; };
  unsigned short* Xbf    = (unsigned short*)alloc((size_t)MROWS*EMB*2);
  unsigned short* Winbf  = (unsigned short*)alloc((size_t)3*EMB*EMB*2);
  unsigned short* Woutbf = (unsigned short*)alloc((size_t)EMB*EMB*2);
  unsigned short* Qb  = (unsigned short*)alloc((size_t)BH*SEQ*HD*2);
  unsigned short* Kbf = (unsigned short*)alloc((size_t)BH*SEQ*HD*2);
  unsigned short* Vb  = (unsigned short*)alloc((size_t)BH*SEQ*HD*2);
  unsigned short* Vt  = (unsigned short*)alloc((size_t)BH*SEQ*HD*2);
  unsigned short* ctx = Xbf;   // Xbf dead after QKV GEMM -> reuse

  k_cvt<<<2048, 256, 0, stream>>>(x,     Xbf,    MROWS*EMB/4);
  k_cvt<<<1024, 256, 0, stream>>>(W_in,  Winbf,  3*EMB*EMB/4);
  k_cvt<<<512,  256, 0, stream>>>(W_out, Woutbf, EMB*EMB/4);

  k_gemm_bt<1><<<dim3(3*EMB/128, MROWS/128), 256, 0, stream>>>(
      Xbf, Winbf, b_in, nullptr, Qb, Kbf, Vb, MROWS, 3*EMB, EMB);

  k_transposeV<<<dim3(SEQ/64, BH), 256, 0, stream>>>(Vb, Vt);

  k_attn5<<<1024, 512, 0, stream>>>(Qb, Kbf, Vt, attnP, ctx);

  k_gemm_bt<0><<<dim3(EMB/128, MROWS/128), 256, 0, stream>>>(
      ctx, Woutbf, b_out, out, nullptr, nullptr, nullptr, MROWS, EMB, EMB);
}

// Round 16
// 368.512 us; speedup vs baseline: 1.0700x; 1.0066x over previous
//
#include <hip/hip_runtime.h>
#include <stdint.h>

#define SEQ 2048
#define BSZ 4
#define EMB 1024
#define NH  16
#define HD  64
#define BH  (BSZ*NH)        // 64
#define MROWS (SEQ*BSZ)     // 8192

typedef __attribute__((ext_vector_type(8))) short short8;
typedef __attribute__((ext_vector_type(4))) float f32x4;
typedef __attribute__((ext_vector_type(4))) unsigned short us4;

__device__ __forceinline__ unsigned short f2bf(float f) {
  unsigned u = __float_as_uint(f);
  u += 0x7fffu + ((u >> 16) & 1u);          // round-to-nearest-even
  return (unsigned short)(u >> 16);
}

#define GLDS(g, l) __builtin_amdgcn_global_load_lds( \
    (const __attribute__((address_space(1))) void*)(g), \
    (__attribute__((address_space(3))) void*)(l), 16, 0, 0)

// ---------------- fused f32 -> bf16 convert (x, W_in, W_out in one launch) ----------------
__global__ void k_cvt3(const float* __restrict__ x, const float* __restrict__ wi,
                       const float* __restrict__ wo, unsigned short* __restrict__ xb,
                       unsigned short* __restrict__ wib, unsigned short* __restrict__ wob) {
  const int n0 = MROWS*EMB/4, n1 = 3*EMB*EMB/4, n2 = EMB*EMB/4;
  int i = blockIdx.x * blockDim.x + threadIdx.x;
  const int stride = gridDim.x * blockDim.x;
  for (; i < n0+n1+n2; i += stride) {
    const float* src; unsigned short* dst; int j;
    if (i < n0)           { src = x;  dst = xb;  j = i; }
    else if (i < n0+n1)   { src = wi; dst = wib; j = i - n0; }
    else                  { src = wo; dst = wob; j = i - n0 - n1; }
    float4 v = reinterpret_cast<const float4*>(src)[j];
    us4 o;
    o[0] = f2bf(v.x); o[1] = f2bf(v.y); o[2] = f2bf(v.z); o[3] = f2bf(v.w);
    reinterpret_cast<us4*>(dst)[j] = o;
  }
}

// ---------------- 128x128-tile bt GEMM: C = A * B^T (+bias) ----------------
template<int MODE>
__global__ __launch_bounds__(256, 2) void k_gemm_bt(
    const unsigned short* __restrict__ A, const unsigned short* __restrict__ B,
    const float* __restrict__ bias, float* __restrict__ outF,
    unsigned short* __restrict__ qb, unsigned short* __restrict__ kb,
    unsigned short* __restrict__ vb, int M, int N, int K)
{
  __shared__ unsigned short As[128*32];
  __shared__ unsigned short Bs[128*32];
  const int tid  = threadIdx.x;
  const int lane = tid & 63;
  const int wid  = tid >> 6;
  const int wr = wid >> 1, wc = wid & 1;
  const int r0 = blockIdx.y * 128;
  const int c0 = blockIdx.x * 128;
  const int lr = lane & 15;
  const int hi = lane >> 4;

  f32x4 acc[4][4];
  #pragma unroll
  for (int i = 0; i < 4; i++)
    #pragma unroll
    for (int j = 0; j < 4; j++) acc[i][j] = f32x4{0.f,0.f,0.f,0.f};

  const int nk = K >> 5;
  for (int kt = 0; kt < nk; ++kt) {
    #pragma unroll
    for (int j = 0; j < 2; ++j) {
      int e = (wid*2 + j)*512 + lane*8;
      int row = e >> 5, kk = e & 31;
      GLDS(A + (size_t)(r0 + row)*K + kt*32 + kk, &As[(wid*2+j)*512]);
      GLDS(B + (size_t)(c0 + row)*K + kt*32 + kk, &Bs[(wid*2+j)*512]);
    }
    __syncthreads();
    short8 af[4], bf[4];
    #pragma unroll
    for (int i = 0; i < 4; i++) af[i] = *(const short8*)&As[(wr*64 + i*16 + lr)*32 + hi*8];
    #pragma unroll
    for (int j = 0; j < 4; j++) bf[j] = *(const short8*)&Bs[(wc*64 + j*16 + lr)*32 + hi*8];
    #pragma unroll
    for (int i = 0; i < 4; i++)
      #pragma unroll
      for (int j = 0; j < 4; j++)
        acc[i][j] = __builtin_amdgcn_mfma_f32_16x16x32_bf16(af[i], bf[j], acc[i][j], 0, 0, 0);
    __syncthreads();
  }

  #pragma unroll
  for (int i = 0; i < 4; i++) {
    #pragma unroll
    for (int j = 0; j < 4; j++) {
      #pragma unroll
      for (int r = 0; r < 4; r++) {
        int row = r0 + wr*64 + i*16 + hi*4 + r;
        int col = c0 + wc*64 + j*16 + lr;
        float v = acc[i][j][r] + bias[col];
        if (MODE == 0) {
          outF[(size_t)row*N + col] = v;
        } else {
          int s = row >> 2, b = row & 3;
          int which = col >> 10, h = (col >> 6) & 15, d = col & 63;
          unsigned short bvv = f2bf(v);
          unsigned short* dst = (which == 0) ? qb : (which == 1) ? kb : vb;
          dst[((size_t)(b*NH + h)*SEQ + s)*HD + d] = bvv;
        }
      }
    }
  }
}

// ---------------- V [bh][s][d] -> Vt [bh][d][s] ----------------
__global__ void k_transposeV(const unsigned short* __restrict__ V, unsigned short* __restrict__ Vt) {
  __shared__ unsigned short T[64][65];
  const int bh = blockIdx.y;
  const int s0 = blockIdx.x * 64;
  const int t = threadIdx.x;             // 0..255, 16 elems each
  const int e = t * 16;
  {
    const int s = e >> 6, d0 = e & 63;
    short8 v0 = *(const short8*)&V[((size_t)bh*SEQ + s0 + s)*HD + d0];
    short8 v1 = *(const short8*)&V[((size_t)bh*SEQ + s0 + s)*HD + d0 + 8];
    #pragma unroll
    for (int q = 0; q < 8; q++) { T[s][d0+q] = (unsigned short)v0[q]; T[s][d0+8+q] = (unsigned short)v1[q]; }
  }
  __syncthreads();
  {
    const int d = e >> 6, sl = e & 63;
    short8 w0, w1;
    #pragma unroll
    for (int q = 0; q < 8; q++) { w0[q] = (short)T[sl+q][d]; w1[q] = (short)T[sl+8+q][d]; }
    *(short8*)&Vt[((size_t)bh*HD + d)*SEQ + s0 + sl]     = w0;
    *(short8*)&Vt[((size_t)bh*HD + d)*SEQ + s0 + sl + 8] = w1;
  }
}

// ---------------- fused attention v5 (verified 367-371us total): counted vmcnt ----------------
// Counting discipline: s_waitcnt vmcnt(N) guarantees all but the newest N VMEM
// ops retired -> to require op X complete, N = #ops issued AFTER X.
// Pass 1 (1 GLDS/iter): after issuing G(kt+2), G(kt+1) has 1 newer op -> vmcnt(1).
// Pass 2 (4 NT stores + 2 GLDS/iter): G(kt+1) has 4+2=6 newer -> vmcnt(6);
// prologue K0,V0 have 2 newer (K1,V1) -> vmcnt(2); kt=30 tail -> vmcnt(4).
__global__ __launch_bounds__(512, 4) void k_attn5(
    const unsigned short* __restrict__ Q, const unsigned short* __restrict__ Kb,
    const unsigned short* __restrict__ Vt, float* __restrict__ P,
    unsigned short* __restrict__ ctx)
{
  __shared__ unsigned short Ks[3][4096];   // [64 k][64 d] swizzled, 8KB each
  __shared__ unsigned short Vs[3][4096];   // [64 d][64 k] swizzled, 8KB each
  __shared__ float Pf[8][1024];            // per-wave [16 q][64 k] f32, swizzled

  const int i   = blockIdx.x;
  const int bh  = i & 63;                  // XCD = bh & 7 for all 16 row-blocks
  const int rb  = i >> 6;

  const int tid = threadIdx.x;
  const int lane = tid & 63, w = tid >> 6;
  const int lr = lane & 15, hi = lane >> 4;
  const int q0 = rb * 128 + w * 16;
  const size_t qkBase = (size_t)bh * SEQ * HD;
  const size_t vtBase = (size_t)bh * HD * SEQ;

  // staging: thread t fills LDS bytes [t*16, t*16+16); global col pre-swizzled
  const int srow = tid >> 3;                                      // 0..63
  const int scol = ((((tid & 7) * 16) ^ ((srow & 7) << 4)) >> 1); // elems
  const int swz  = (lr & 7) << 4;

  #define STG_K(buf, kt) GLDS(Kb + qkBase + (size_t)((kt)*64 + srow)*HD + scol, \
                              (unsigned short*)Ks[buf] + tid*8)
  #define STG_V(buf, kt) GLDS(Vt + vtBase + (size_t)srow*SEQ + (kt)*64 + scol, \
                              (unsigned short*)Vs[buf] + tid*8)
  #define WAITV(n) asm volatile("s_waitcnt vmcnt(" #n ")" ::: "memory")
  #define BARRIER __builtin_amdgcn_s_barrier(); asm volatile("" ::: "memory")

  // Q B-fragments (two K=32 d-slices)
  short8 bq0 = *(const short8*)&Q[qkBase + (size_t)(q0 + lr)*HD + hi*8];
  short8 bq1 = *(const short8*)&Q[qkBase + (size_t)(q0 + lr)*HD + 32 + hi*8];

  // ---- pass 1: row sums of exp(s/8) ----
  STG_K(0, 0); STG_K(1, 1);
  WAITV(1);                        // K0 landed (K1 may float)
  BARRIER;
  float lsum = 0.f;
  {
    int cur = 0;
    for (int kt = 0; kt < 32; ++kt) {
      const char* kbase = (const char*)Ks[cur];
      #pragma unroll
      for (int ct = 0; ct < 4; ++ct) {
        const int rowb = (ct*16 + lr) * 128;
        short8 ak0 = *(const short8*)(kbase + ((rowb + hi*16) ^ swz));
        short8 ak1 = *(const short8*)(kbase + ((rowb + 64 + hi*16) ^ swz));
        f32x4 z = f32x4{0.f,0.f,0.f,0.f};
        z = __builtin_amdgcn_mfma_f32_16x16x32_bf16(ak0, bq0, z, 0, 0, 0);
        z = __builtin_amdgcn_mfma_f32_16x16x32_bf16(ak1, bq1, z, 0, 0, 0);
        lsum += __expf(z[0]*0.125f) + __expf(z[1]*0.125f)
              + __expf(z[2]*0.125f) + __expf(z[3]*0.125f);
      }
      int bs = cur + 2; if (bs >= 3) bs -= 3;
      if (kt < 30) {
        STG_K(bs, kt + 2);
        WAITV(1);                  // K(kt+1) landed; K(kt+2) floats
      } else {
        WAITV(0);
      }
      BARRIER;
      cur = (cur >= 2) ? 0 : cur + 1;
    }
  }
  float lv = lsum;
  lv += __shfl_xor(lv, 16);
  lv += __shfl_xor(lv, 32);
  const float li = 1.0f / lv;        // 1/l for row q0+lr

  // ---- pass 2: recompute, staged coalesced P store, PV accumulate ----
  f32x4 o[4];
  #pragma unroll
  for (int d = 0; d < 4; ++d) o[d] = f32x4{0.f,0.f,0.f,0.f};

  float* pout = P + ((size_t)bh*SEQ + q0)*SEQ;
  char* pfw = (char*)Pf[w];

  STG_K(0, 0); STG_V(0, 0); STG_K(1, 1); STG_V(1, 1);
  WAITV(2);                        // K0,V0 landed (K1,V1 float)
  BARRIER;
  {
    int cur = 0;
    for (int kt = 0; kt < 32; ++kt) {
      const char* kbase = (const char*)Ks[cur];
      const char* vbase = (const char*)Vs[cur];
      // QK + exp -> Pf (swizzled f32 tile)
      #pragma unroll
      for (int ct = 0; ct < 4; ++ct) {
        const int rowb = (ct*16 + lr) * 128;
        short8 ak0 = *(const short8*)(kbase + ((rowb + hi*16) ^ swz));
        short8 ak1 = *(const short8*)(kbase + ((rowb + 64 + hi*16) ^ swz));
        f32x4 z = f32x4{0.f,0.f,0.f,0.f};
        z = __builtin_amdgcn_mfma_f32_16x16x32_bf16(ak0, bq0, z, 0, 0, 0);
        z = __builtin_amdgcn_mfma_f32_16x16x32_bf16(ak1, bq1, z, 0, 0, 0);
        f32x4 e;
        #pragma unroll
        for (int r = 0; r < 4; r++) e[r] = __expf(z[r]*0.125f) * li;
        *(f32x4*)(pfw + ((((ct*4 + hi) ^ lr) << 4) + lr*256)) = e;
      }
      // coalesced NT P stores: 4 insts, each 4 rows x 256B
      #pragma unroll
      for (int j = 0; j < 4; ++j) {
        const int row = j*4 + hi;
        f32x4 pv4 = *(const f32x4*)(pfw + (row*256 + ((lr ^ row) << 4)));
        __builtin_nontemporal_store(pv4,
            (f32x4*)&pout[(size_t)row*SEQ + kt*64 + lr*4]);
      }
      // PV: pa frags from Pf (cvt f32->bf16), V frags from Vs
      #pragma unroll
      for (int s = 0; s < 2; ++s) {
        const int c0 = s*8 + hi*2;
        f32x4 f0 = *(const f32x4*)(pfw + (lr*256 + (((c0    ) ^ lr) << 4)));
        f32x4 f1 = *(const f32x4*)(pfw + (lr*256 + (((c0 + 1) ^ lr) << 4)));
        short8 pa;
        #pragma unroll
        for (int r = 0; r < 4; r++) { pa[r] = (short)f2bf(f0[r]); pa[4+r] = (short)f2bf(f1[r]); }
        #pragma unroll
        for (int dt = 0; dt < 4; ++dt) {
          const int rowb = (dt*16 + lr) * 128;
          short8 vb = *(const short8*)(vbase + ((rowb + s*64 + hi*16) ^ swz));
          o[dt] = __builtin_amdgcn_mfma_f32_16x16x32_bf16(pa, vb, o[dt], 0, 0, 0);
        }
      }
      if (kt < 30) {
        int bs = cur + 2; if (bs >= 3) bs -= 3;
        STG_K(bs, kt + 2); STG_V(bs, kt + 2);
        WAITV(6);                  // K/V(kt+1) landed (newer: 4 stores + 2 GLDS)
        BARRIER;
      } else if (kt == 30) {
        WAITV(4);                  // K/V(31) landed (newer: 4 stores)
        BARRIER;
      }
      // kt == 31: nothing reads K/V LDS afterwards -> no wait, no barrier
      cur = (cur >= 2) ? 0 : cur + 1;
    }
  }

  // ---- ctx store: [s*B + b][h*64 + d] bf16 ----
  const int b = bh >> 4, h = bh & 15;
  #pragma unroll
  for (int dt = 0; dt < 4; ++dt)
    #pragma unroll
    for (int r = 0; r < 4; r++) {
      int s = q0 + hi*4 + r;
      ctx[((size_t)s*BSZ + b)*EMB + h*HD + dt*16 + lr] = f2bf(o[dt][r]);
    }
  #undef STG_K
  #undef STG_V
  #undef WAITV
  #undef BARRIER
}

extern "C" void kernel_launch(void* const* d_in, const int* in_sizes, int n_in,
                              void* d_out, int out_size, void* d_ws, size_t ws_size,
                              hipStream_t stream) {
  const float* x     = (const float*)d_in[0];
  const float* W_in  = (const float*)d_in[1];
  const float* b_in  = (const float*)d_in[2];
  const float* W_out = (const float*)d_in[3];
  const float* b_out = (const float*)d_in[4];
  float* out   = (float*)d_out;
  float* attnP = out + (size_t)MROWS*EMB;

  char* ws = (char*)d_ws;
  size_t off = 0;
  auto alloc = [&](size_t bytes) { char* p = ws + off; off += (bytes + 255) & ~255ULL; return p; };
  unsigned short* Xbf    = (unsigned short*)alloc((size_t)MROWS*EMB*2);
  unsigned short* Winbf  = (unsigned short*)alloc((size_t)3*EMB*EMB*2);
  unsigned short* Woutbf = (unsigned short*)alloc((size_t)EMB*EMB*2);
  unsigned short* Qb  = (unsigned short*)alloc((size_t)BH*SEQ*HD*2);
  unsigned short* Kbf = (unsigned short*)alloc((size_t)BH*SEQ*HD*2);
  unsigned short* Vb  = (unsigned short*)alloc((size_t)BH*SEQ*HD*2);
  unsigned short* Vt  = (unsigned short*)alloc((size_t)BH*SEQ*HD*2);
  unsigned short* ctx = Xbf;   // Xbf dead after QKV GEMM -> reuse

  k_cvt3<<<2048, 256, 0, stream>>>(x, W_in, W_out, Xbf, Winbf, Woutbf);

  k_gemm_bt<1><<<dim3(3*EMB/128, MROWS/128), 256, 0, stream>>>(
      Xbf, Winbf, b_in, nullptr, Qb, Kbf, Vb, MROWS, 3*EMB, EMB);

  k_transposeV<<<dim3(SEQ/64, BH), 256, 0, stream>>>(Vb, Vt);

  k_attn5<<<1024, 512, 0, stream>>>(Qb, Kbf, Vt, attnP, ctx);

  k_gemm_bt<0><<<dim3(EMB/128, MROWS/128), 256, 0, stream>>>(
      ctx, Woutbf, b_out, out, nullptr, nullptr, nullptr, MROWS, EMB, EMB);
}